// Round 1
// baseline (744.716 us; speedup 1.0000x reference)
//
#include <hip/hip_runtime.h>
#include <math.h>

typedef unsigned long long u64;
typedef unsigned int u32;
typedef unsigned char u8;

#define BUCKETS 16384
#define CAND_CAP 8192
#define OWN_MAX 8

__device__ __forceinline__ u64 mix64(u64 x) {
  x ^= x >> 33; x *= 0xff51afd7ed558ccdULL;
  x ^= x >> 33; x *= 0xc4ceb9fe1a85ec53ULL;
  x ^= x >> 33;
  return x;
}

// dw = 0.71f^qw for qw in [-15, 0]; table index is -qw. Computed in double so the
// f32 result is correctly rounded == glibc powf(0.71f, qw) used by the np reference.
__device__ __forceinline__ void fill_dwtab(float* dwtab) {
  if (threadIdx.x < 16) {
    double p = 1.0;
    const double a = (double)0.71f;  // 0.709999978542327881
    for (int j = 0; j < (int)threadIdx.x; ++j) p *= a;
    dwtab[threadIdx.x] = (float)(1.0 / p);
  }
  __syncthreads();
}

__device__ __forceinline__ u64 cell_key(float cx, float cy, float tw, float th,
                                        float off, const float* dwtab) {
  const float STEP = (float)(1.0 / 0.71 - 1.0);  // f32(0.40845070422535207)
  float qwf = floorf(tw + off);
  float qhf = floorf(th + off);
  int qw = (int)qwf;
  int qh = (int)qhf;
  int wi = -qw; wi = wi < 0 ? 0 : (wi > 15 ? 15 : wi);
  int hi2 = -qh; hi2 = hi2 < 0 ? 0 : (hi2 > 15 ? 15 : hi2);
  float dw = dwtab[wi];
  float dh = dwtab[hi2];
  int qx = (int)floorf(cx / (STEP * dw) + off);
  int qy = (int)floorf(cy / (STEP * dh) + off);
  int key_hi = (qw + 64) * 128 + (qh + 64);   // >= 50*128+50 > 0, so key 0 == EMPTY
  int key_lo = qx * 65536 + qy;
  return ((u64)(u32)key_hi << 32) | (u64)(u32)key_lo;
}

__device__ __forceinline__ float tval(float w) {
  const float LOG_A = (float)-0.34249033916884865;  // f32(log(f32(0.71)))
  return (float)log((double)w) / LOG_A;  // correctly-rounded f32 log, then f32 divide
}

__global__ void __launch_bounds__(256) hnms_insert(
    const float4* __restrict__ rects, const float* __restrict__ scores,
    const int* __restrict__ nump, u64* __restrict__ tkeys, u64* __restrict__ tvals,
    int N, int H, int m0, int mcap) {
  __shared__ float dwtab[16];
  fill_dwtab(dwtab);
  int i = blockIdx.x * blockDim.x + threadIdx.x;
  if (i >= N) return;
  float4 r = rects[i];
  float s = scores[i];
  int num = *nump;
  float tw = tval(r.z);
  float th = tval(r.w);
  u64 packed = ((u64)__float_as_uint(s) << 32) | (u64)(u32)(~(u32)i);
  u32 mask = (u32)(H - 1);
  int mend = num < (m0 + mcap) ? num : (m0 + mcap);
  for (int m = m0; m < mend; ++m) {
    float off = (float)((double)m / (double)num);
    u64 key = cell_key(r.x, r.y, tw, th, off, dwtab);
    u64* keys = tkeys + (size_t)(m - m0) * (size_t)H;
    u64* vals = tvals + (size_t)(m - m0) * (size_t)H;
    u32 slot = (u32)mix64(key) & mask;
    bool claimed = false;
    for (int p = 0; p < H; ++p) {
      u64 k = keys[slot];
      if (k == key) { claimed = true; break; }
      if (k == 0ULL) {
        u64 old = atomicCAS(&keys[slot], 0ULL, key);
        if (old == 0ULL || old == key) { claimed = true; break; }
      }
      slot = (slot + 1u) & mask;
    }
    if (claimed) atomicMax(&vals[slot], packed);
  }
}

__global__ void __launch_bounds__(256) hnms_check(
    const float4* __restrict__ rects, const float* __restrict__ scores,
    const int* __restrict__ nump, const u64* __restrict__ tkeys,
    const u64* __restrict__ tvals, u8* __restrict__ keep,
    int N, int H, int m0, int mcap) {
  __shared__ float dwtab[16];
  fill_dwtab(dwtab);
  int i = blockIdx.x * blockDim.x + threadIdx.x;
  if (i >= N) return;
  float4 r = rects[i];
  float s = scores[i];
  int num = *nump;
  float tw = tval(r.z);
  float th = tval(r.w);
  u64 packed = ((u64)__float_as_uint(s) << 32) | (u64)(u32)(~(u32)i);
  u32 mask = (u32)(H - 1);
  int mend = num < (m0 + mcap) ? num : (m0 + mcap);
  bool lose = false;
  for (int m = m0; m < mend; ++m) {
    float off = (float)((double)m / (double)num);
    u64 key = cell_key(r.x, r.y, tw, th, off, dwtab);
    const u64* keys = tkeys + (size_t)(m - m0) * (size_t)H;
    const u64* vals = tvals + (size_t)(m - m0) * (size_t)H;
    u32 slot = (u32)mix64(key) & mask;
    u64 win = 0ULL;
    for (int p = 0; p < H; ++p) {
      u64 k = keys[slot];
      if (k == key) { win = vals[slot]; break; }
      if (k == 0ULL) break;
      slot = (slot + 1u) & mask;
    }
    if (win != 0ULL && win != packed) lose = true;
  }
  if (lose) keep[i] = 0;
}

__global__ void __launch_bounds__(256) hist_kernel(
    const float* __restrict__ scores, const u8* __restrict__ keep,
    u32* __restrict__ hist, int N) {
  int i = blockIdx.x * blockDim.x + threadIdx.x;
  if (i >= N) return;
  if (!keep[i]) return;
  float s = scores[i];
  int b = (int)(s * (float)BUCKETS);  // exact: power-of-two scale, s in [0,1)
  b = b < 0 ? 0 : (b >= BUCKETS ? BUCKETS - 1 : b);
  atomicAdd(&hist[b], 1u);
}

__global__ void __launch_bounds__(1024) thresh_kernel(
    const u32* __restrict__ hist, u32* __restrict__ meta, int K) {
  __shared__ u32 part[1024];
  int t = threadIdx.x;
  u32 chunk[16];
  u32 mysum = 0;
  int base = t * 16;
  for (int j = 0; j < 16; ++j) { chunk[j] = hist[base + j]; mysum += chunk[j]; }
  part[t] = mysum;
  __syncthreads();
  u32 inc = mysum;
  for (int d = 1; d < 1024; d <<= 1) {
    u32 v = (t + d < 1024) ? part[t + d] : 0u;
    __syncthreads();
    inc += v;
    part[t] = inc;
    __syncthreads();
  }
  u32 prev = inc - mysum;  // cum over buckets >= base+16
  for (int j = 15; j >= 0; --j) {
    u32 cumb = prev + chunk[j];
    if (cumb >= (u32)K && prev < (u32)K) { meta[0] = (u32)(base + j); meta[1] = cumb; }
    prev = cumb;
  }
  if (t == 0 && prev < (u32)K) { meta[0] = 0u; meta[1] = prev; }
}

__global__ void __launch_bounds__(256) gather_kernel(
    const float* __restrict__ scores, const u8* __restrict__ keep,
    const u32* __restrict__ meta, u64* __restrict__ cand,
    u32* __restrict__ ccount, int N) {
  int i = blockIdx.x * blockDim.x + threadIdx.x;
  if (i >= N) return;
  if (!keep[i]) return;
  float s = scores[i];
  int b = (int)(s * (float)BUCKETS);
  b = b < 0 ? 0 : (b >= BUCKETS ? BUCKETS - 1 : b);
  if ((u32)b < meta[0]) return;
  u32 pos = atomicAdd(ccount, 1u);
  if (pos < CAND_CAP)
    cand[pos] = ((u64)__float_as_uint(s) << 32) | (u64)(u32)(~(u32)i);
}

__global__ void __launch_bounds__(1024) topk_finalize(
    const float4* __restrict__ rects, const u64* __restrict__ cand,
    const u32* __restrict__ meta, float* __restrict__ out, int K) {
  int C = (int)meta[2];
  if (C > CAND_CAP) C = CAND_CAP;
  __shared__ u64 tile[1024];
  u64 mine[OWN_MAX];
  int rank[OWN_MAX];
  int own = 0;
  for (int j = (int)threadIdx.x; j < C; j += 1024) {
    if (own < OWN_MAX) { mine[own] = cand[j]; rank[own] = 0; own++; }
  }
  for (int t0 = 0; t0 < C; t0 += 1024) {
    int idx = t0 + (int)threadIdx.x;
    __syncthreads();
    tile[threadIdx.x] = (idx < C) ? cand[idx] : 0ULL;
    __syncthreads();
    int lim = (C - t0) < 1024 ? (C - t0) : 1024;
    for (int k = 0; k < lim; ++k) {
      u64 v = tile[k];
      for (int o = 0; o < own; ++o) rank[o] += (v > mine[o]) ? 1 : 0;
    }
  }
  for (int o = 0; o < own; ++o) {
    int rk = rank[o];
    if (rk < K) {
      u32 inv = (u32)(mine[o] & 0xffffffffULL);
      u32 bi = ~inv;
      float s = __uint_as_float((u32)(mine[o] >> 32));
      float4 b = rects[bi];
      out[rk * 5 + 0] = b.x;
      out[rk * 5 + 1] = b.y;
      out[rk * 5 + 2] = b.z;
      out[rk * 5 + 3] = b.w;
      out[rk * 5 + 4] = s;
    }
  }
  for (int rk = C + (int)threadIdx.x; rk < K; rk += 1024) {
    out[rk * 5 + 0] = 0.0f;
    out[rk * 5 + 1] = 0.0f;
    out[rk * 5 + 2] = 0.0f;
    out[rk * 5 + 3] = 0.0f;
    out[rk * 5 + 4] = 0.0f;
  }
}

extern "C" void kernel_launch(void* const* d_in, const int* in_sizes, int n_in,
                              void* d_out, int out_size, void* d_ws, size_t ws_size,
                              hipStream_t stream) {
  const float4* rects = (const float4*)d_in[0];
  const float* scores = (const float*)d_in[1];
  const int* nump = (const int*)d_in[2];
  int N = in_sizes[1];
  int K = out_size / 5;
  float* out = (float*)d_out;

  char* ws = (char*)d_ws;
  u32* hist = (u32*)ws;                                   // 64 KB
  u32* meta = (u32*)(ws + BUCKETS * 4);                   // [0]=T, [1]=cum, [2]=cand count
  u64* cand = (u64*)(ws + BUCKETS * 4 + 256);             // 64 KB
  u8* keep = (u8*)(ws + BUCKETS * 4 + 256 + CAND_CAP * 8);
  size_t tab_off = (size_t)(BUCKETS * 4 + 256 + CAND_CAP * 8) + (size_t)N;
  tab_off = (tab_off + 255) & ~(size_t)255;

  int H = 1 << 21;  // 2M slots/table >= 1M max distinct keys -> never full
  size_t per_table = (size_t)H * 16ULL;
  size_t avail = ws_size > tab_off ? ws_size - tab_off : 0;

  hipMemsetAsync(hist, 0, BUCKETS * 4 + 256, stream);
  hipMemsetAsync(keep, 1, (size_t)N, stream);

  int threads = 256;
  int blocks = (N + threads - 1) / threads;

  if (avail >= 4 * per_table) {
    u64* tkeys = (u64*)(ws + tab_off);
    u64* tvals = (u64*)(ws + tab_off + 4ULL * (size_t)H * 8ULL);
    hipMemsetAsync(tkeys, 0, 4 * per_table, stream);
    hnms_insert<<<blocks, threads, 0, stream>>>(rects, scores, nump, tkeys, tvals, N, H, 0, 4);
    hnms_check<<<blocks, threads, 0, stream>>>(rects, scores, nump, tkeys, tvals, keep, N, H, 0, 4);
  } else {
    if (avail < per_table && avail >= ((size_t)(1 << 20) * 16ULL)) {
      H = 1 << 20;
      per_table = (size_t)H * 16ULL;
    }
    u64* tkeys = (u64*)(ws + tab_off);
    u64* tvals = (u64*)(ws + tab_off + (size_t)H * 8ULL);
    for (int m = 0; m < 4; ++m) {
      hipMemsetAsync(tkeys, 0, per_table, stream);
      hnms_insert<<<blocks, threads, 0, stream>>>(rects, scores, nump, tkeys, tvals, N, H, m, 1);
      hnms_check<<<blocks, threads, 0, stream>>>(rects, scores, nump, tkeys, tvals, keep, N, H, m, 1);
    }
  }

  hist_kernel<<<blocks, threads, 0, stream>>>(scores, keep, hist, N);
  thresh_kernel<<<1, 1024, 0, stream>>>(hist, meta, K);
  gather_kernel<<<blocks, threads, 0, stream>>>(scores, keep, meta, cand, meta + 2, N);
  topk_finalize<<<1, 1024, 0, stream>>>(rects, cand, meta, out, K);
}

// Round 2
// 402.814 us; speedup vs baseline: 1.8488x; 1.8488x over previous
//
#include <hip/hip_runtime.h>
#include <math.h>

typedef unsigned long long u64;
typedef unsigned int u32;
typedef unsigned char u8;

#define BUCKETS 16384
#define CAND_CAP 8192
#define HASH_BITS 21
// Score-offset so that any stale/poison val (harness poisons ws with 0xAA bytes,
// 0xAAAA... < 0xC000...) always loses atomicMax against a real inserted value.
#define VAL_OFFSET 0xC0000000u

__device__ __forceinline__ u32 mix32(u32 x) {
  x ^= x >> 16; x *= 0x85ebca6bu;
  x ^= x >> 13; x *= 0xc2b2ae35u;
  x ^= x >> 16;
  return x;
}

// dw = 0.71f^qw for qw in [-15, 0]; table index is -qw. Computed in double so the
// f32 result is correctly rounded == glibc powf used by the np reference.
__device__ __forceinline__ void fill_dwtab(float* dwtab) {
  if (threadIdx.x < 16) {
    double p = 1.0;
    const double a = (double)0.71f;  // 0.709999978542327881
    for (int j = 0; j < (int)threadIdx.x; ++j) p *= a;
    dwtab[threadIdx.x] = (float)(1.0 / p);
  }
  __syncthreads();
}

// Compact 32-bit cell key. Ranges (w,h in [1,100], cx,cy in [0,1000)):
// qw,qh in [-14,0] -> +15 in [1,15] (4 bits, key always nonzero);
// qx,qy in [0,2450) (12 bits). Arithmetic identical to the round-1 kernel
// that validated with absmax 0.0 vs the np reference.
__device__ __forceinline__ u32 cell_key32(float cx, float cy, float tw, float th,
                                          float off, const float* dwtab) {
  const float STEP = (float)(1.0 / 0.71 - 1.0);  // f32(0.40845070422535207)
  int qw = (int)floorf(tw + off);
  int qh = (int)floorf(th + off);
  int wi = -qw; wi = wi < 0 ? 0 : (wi > 15 ? 15 : wi);
  int hi2 = -qh; hi2 = hi2 < 0 ? 0 : (hi2 > 15 ? 15 : hi2);
  float dw = dwtab[wi];
  float dh = dwtab[hi2];
  int qx = (int)floorf(cx / (STEP * dw) + off);
  int qy = (int)floorf(cy / (STEP * dh) + off);
  return ((u32)(qw + 15) << 28) | ((u32)(qh + 15) << 24) |
         (((u32)qx & 0xFFFu) << 12) | ((u32)qy & 0xFFFu);
}

__device__ __forceinline__ float tval(float w) {
  const float LOG_A = (float)-0.34249033916884865;  // f32(log(f32(0.71)))
  return (float)log((double)w) / LOG_A;  // correctly-rounded f32 log, then f32 divide
}

__device__ __forceinline__ u64 pack_val(float s, u32 i) {
  return ((u64)(__float_as_uint(s) + VAL_OFFSET) << 32) | (u64)(~i);
}

__global__ void __launch_bounds__(256) hnms_insert(
    const float4* __restrict__ rects, const float* __restrict__ scores,
    const int* __restrict__ nump, u32* __restrict__ tkeys, u64* __restrict__ tvals,
    u32* __restrict__ slotrec, int N, int H, int m0, int mcap) {
  __shared__ float dwtab[16];
  fill_dwtab(dwtab);
  int i = blockIdx.x * blockDim.x + threadIdx.x;
  if (i >= N) return;
  float4 r = rects[i];
  float s = scores[i];
  int num = *nump;
  float tw = tval(r.z);
  float th = tval(r.w);
  u64 packed = pack_val(s, (u32)i);
  u32 mask = (u32)(H - 1);
  int mend = num < (m0 + mcap) ? num : (m0 + mcap);
  for (int m = m0; m < mend; ++m) {
    float off = (float)((double)m / (double)num);
    u32 key = cell_key32(r.x, r.y, tw, th, off, dwtab);
    u32* keys = tkeys + (size_t)(m - m0) * (size_t)H;
    u64* vals = tvals + (size_t)(m - m0) * (size_t)H;
    u32 slot = mix32(key) & mask;
    for (int p = 0; p < H; ++p) {
      u32 k = keys[slot];
      if (k == key) break;
      if (k == 0u) {
        u32 old = atomicCAS(&keys[slot], 0u, key);
        if (old == 0u || old == key) break;
      }
      slot = (slot + 1u) & mask;
    }
    atomicMax(&vals[slot], packed);
    slotrec[(size_t)(m - m0) * (size_t)N + (size_t)i] = slot;
  }
}

// Check pass: no re-probe, no transcendentals — just vals[slotrec] compares.
// Optionally fuses the score histogram for survivors (fused 4-table path).
__global__ void __launch_bounds__(256) hnms_check(
    const float* __restrict__ scores, const int* __restrict__ nump,
    const u64* __restrict__ tvals, const u32* __restrict__ slotrec,
    u8* __restrict__ keep, u32* __restrict__ hist,
    int N, int H, int m0, int mcap, int do_hist) {
  int i = blockIdx.x * blockDim.x + threadIdx.x;
  if (i >= N) return;
  float s = scores[i];
  int num = *nump;
  u64 packed = pack_val(s, (u32)i);
  int mend = num < (m0 + mcap) ? num : (m0 + mcap);
  bool lose = false;
  for (int m = m0; m < mend; ++m) {
    u32 slot = slotrec[(size_t)(m - m0) * (size_t)N + (size_t)i];
    u64 win = tvals[(size_t)(m - m0) * (size_t)H + (size_t)slot];
    lose = lose || (win != packed);
  }
  u8 kept = keep[i] & (u8)(!lose);
  keep[i] = kept;
  if (do_hist && kept) {
    int b = (int)(s * (float)BUCKETS);  // exact: power-of-two scale, s in [0,1)
    b = b < 0 ? 0 : (b >= BUCKETS ? BUCKETS - 1 : b);
    atomicAdd(&hist[b], 1u);
  }
}

__global__ void __launch_bounds__(256) hist_kernel(
    const float* __restrict__ scores, const u8* __restrict__ keep,
    u32* __restrict__ hist, int N) {
  int i = blockIdx.x * blockDim.x + threadIdx.x;
  if (i >= N) return;
  if (!keep[i]) return;
  float s = scores[i];
  int b = (int)(s * (float)BUCKETS);
  b = b < 0 ? 0 : (b >= BUCKETS ? BUCKETS - 1 : b);
  atomicAdd(&hist[b], 1u);
}

__global__ void __launch_bounds__(1024) thresh_kernel(
    const u32* __restrict__ hist, u32* __restrict__ meta, int K) {
  __shared__ u32 part[1024];
  int t = threadIdx.x;
  u32 chunk[16];
  u32 mysum = 0;
  int base = t * 16;
  for (int j = 0; j < 16; ++j) { chunk[j] = hist[base + j]; mysum += chunk[j]; }
  part[t] = mysum;
  __syncthreads();
  u32 inc = mysum;
  for (int d = 1; d < 1024; d <<= 1) {
    u32 v = (t + d < 1024) ? part[t + d] : 0u;
    __syncthreads();
    inc += v;
    part[t] = inc;
    __syncthreads();
  }
  u32 prev = inc - mysum;  // count over buckets >= base+16
  for (int j = 15; j >= 0; --j) {
    u32 cumb = prev + chunk[j];  // count over buckets >= base+j
    if (cumb >= (u32)K && prev < (u32)K) { meta[0] = (u32)(base + j); meta[1] = cumb; }
    prev = cumb;
  }
  if (t == 0 && prev < (u32)K) { meta[0] = 0u; meta[1] = prev; }  // fewer kept than K
}

__global__ void __launch_bounds__(256) gather_kernel(
    const float* __restrict__ scores, const u8* __restrict__ keep,
    const u32* __restrict__ meta, u64* __restrict__ cand,
    u32* __restrict__ ccount, int N) {
  int i = blockIdx.x * blockDim.x + threadIdx.x;
  if (i >= N) return;
  if (!keep[i]) return;
  float s = scores[i];
  int b = (int)(s * (float)BUCKETS);
  b = b < 0 ? 0 : (b >= BUCKETS ? BUCKETS - 1 : b);
  if ((u32)b < meta[0]) return;
  u32 pos = atomicAdd(ccount, 1u);
  if (pos < CAND_CAP)
    cand[pos] = ((u64)__float_as_uint(s) << 32) | (u64)(~(u32)i);
}

// Multi-block rank sort: one candidate per thread, rank in a scalar register
// (round-1 version kept per-thread ARRAYS with dynamic indexing -> scratch
// spill -> 259 us on one CU; this is the fix).
__global__ void __launch_bounds__(256) topk_rank(
    const float4* __restrict__ rects, const u64* __restrict__ cand,
    const u32* __restrict__ meta, float* __restrict__ out, int K) {
  int C = (int)meta[2];
  if (C > CAND_CAP) C = CAND_CAP;
  int t = blockIdx.x * blockDim.x + threadIdx.x;
  u64 mine = (t < C) ? cand[t] : 0ULL;
  int rank = 0;
  __shared__ u64 tile[256];
  for (int t0 = 0; t0 < C; t0 += 256) {
    __syncthreads();
    int idx = t0 + (int)threadIdx.x;
    tile[threadIdx.x] = (idx < C) ? cand[idx] : 0ULL;
    __syncthreads();
    int lim = (C - t0) < 256 ? (C - t0) : 256;
    for (int k = 0; k < lim; ++k) rank += (tile[k] > mine) ? 1 : 0;
  }
  if (t < C && rank < K) {
    u32 bi = ~((u32)(mine & 0xffffffffULL));
    float s = __uint_as_float((u32)(mine >> 32));
    float4 b = rects[bi];
    out[rank * 5 + 0] = b.x;
    out[rank * 5 + 1] = b.y;
    out[rank * 5 + 2] = b.z;
    out[rank * 5 + 3] = b.w;
    out[rank * 5 + 4] = s;
  }
  if (t >= C && t < K) {  // zero-fill rows [C, K)
    out[t * 5 + 0] = 0.0f;
    out[t * 5 + 1] = 0.0f;
    out[t * 5 + 2] = 0.0f;
    out[t * 5 + 3] = 0.0f;
    out[t * 5 + 4] = 0.0f;
  }
}

extern "C" void kernel_launch(void* const* d_in, const int* in_sizes, int n_in,
                              void* d_out, int out_size, void* d_ws, size_t ws_size,
                              hipStream_t stream) {
  const float4* rects = (const float4*)d_in[0];
  const float* scores = (const float*)d_in[1];
  const int* nump = (const int*)d_in[2];
  int N = in_sizes[1];
  int K = out_size / 5;
  float* out = (float*)d_out;

  char* ws = (char*)d_ws;
  u32* hist = (u32*)ws;                         // 64 KB
  u32* meta = (u32*)(ws + BUCKETS * 4);         // [0]=T bucket, [1]=cum, [2]=cand count
  u64* cand = (u64*)(ws + BUCKETS * 4 + 256);   // 64 KB
  size_t off = (size_t)BUCKETS * 4 + 256 + (size_t)CAND_CAP * 8;
  u8* keep = (u8*)(ws + off);
  off += (size_t)N;
  off = (off + 255) & ~(size_t)255;
  u32* slotrec = (u32*)(ws + off);              // up to 4*N u32 (16 MB)
  size_t slotrec_max = 4ULL * (size_t)N * 4ULL;
  size_t tab_off = (off + slotrec_max + 255) & ~(size_t)255;

  int H = 1 << HASH_BITS;                       // 2M slots/table >= 1M distinct keys
  size_t keys_b = (size_t)H * 4ULL;
  size_t vals_b = (size_t)H * 8ULL;
  size_t avail = ws_size > tab_off ? ws_size - tab_off : 0;

  hipMemsetAsync(hist, 0, BUCKETS * 4 + 256, stream);   // hist + meta (incl. cand count)
  hipMemsetAsync(keep, 1, (size_t)N, stream);

  int threads = 256;
  int blocks = (N + threads - 1) / threads;
  int topk_cover = CAND_CAP > K ? CAND_CAP : K;
  int topk_blocks = (topk_cover + 255) / 256;

  if (avail >= 4 * (keys_b + vals_b)) {
    // Fused path: 4 tables (keys[4][H] then vals[4][H] contiguous; 96 MB memset).
    u32* tkeys = (u32*)(ws + tab_off);
    u64* tvals = (u64*)(ws + tab_off + 4 * keys_b);
    hipMemsetAsync(tkeys, 0, 4 * (keys_b + vals_b), stream);
    hnms_insert<<<blocks, threads, 0, stream>>>(rects, scores, nump, tkeys, tvals,
                                                slotrec, N, H, 0, 4);
    hnms_check<<<blocks, threads, 0, stream>>>(scores, nump, tvals, slotrec, keep,
                                               hist, N, H, 0, 4, 1);
  } else {
    // Small-workspace path: one table reused across m (kernels no-op for m >= num).
    if (avail < (keys_b + vals_b)) {
      H = 1 << 20; keys_b = (size_t)H * 4ULL; vals_b = (size_t)H * 8ULL;
    }
    u32* tkeys = (u32*)(ws + tab_off);
    u64* tvals = (u64*)(ws + tab_off + keys_b);
    for (int m = 0; m < 4; ++m) {
      hipMemsetAsync(tkeys, 0, keys_b + vals_b, stream);
      hnms_insert<<<blocks, threads, 0, stream>>>(rects, scores, nump, tkeys, tvals,
                                                  slotrec, N, H, m, 1);
      hnms_check<<<blocks, threads, 0, stream>>>(scores, nump, tvals, slotrec, keep,
                                                 hist, N, H, m, 1, 0);
    }
    hist_kernel<<<blocks, threads, 0, stream>>>(scores, keep, hist, N);
  }

  thresh_kernel<<<1, 1024, 0, stream>>>(hist, meta, K);
  gather_kernel<<<blocks, threads, 0, stream>>>(scores, keep, meta, cand, meta + 2, N);
  topk_rank<<<topk_blocks, threads, 0, stream>>>(rects, cand, meta, out, K);
}